// Round 2
// baseline (1596.540 us; speedup 1.0000x reference)
//
#include <hip/hip_runtime.h>

#define D_IN   128
#define HEADS  8
#define FOUT   64
#define NOUT   16   // 8 src + 8 trg folded outputs

// ---------------------------------------------------------------------------
// Detect whether edge_index arrived as int32 or int64 (little-endian).
// If int64, every odd 32-bit word of the buffer (high halves) is zero.
// flag == 0 -> int64 layout ; flag != 0 -> int32 layout.
__global__ void k_detect(const unsigned int* __restrict__ idx_w, int nwords,
                         unsigned int* __restrict__ flag) {
    unsigned int local = 0;
    int stride = gridDim.x * blockDim.x;
    for (int i = blockIdx.x * blockDim.x + threadIdx.x; 2 * i + 1 < nwords; i += stride)
        local |= idx_w[2 * i + 1];
    if (__any(local != 0) && (threadIdx.x & 63) == 0)
        atomicOr(flag, 1u);
}

// ---------------------------------------------------------------------------
// Fold scoring vectors into the projection (Wc is [16][128] transposed).
__global__ void k_fold_w(const float* __restrict__ W,
                         const float* __restrict__ a_src,
                         const float* __restrict__ a_trg,
                         float* __restrict__ Wc) {
    int t = blockIdx.x * blockDim.x + threadIdx.x;
    if (t >= D_IN * HEADS) return;
    int d = t >> 3, h = t & 7;
    const float* wrow = W + d * (HEADS * FOUT) + h * FOUT;
    float s1 = 0.f, s2 = 0.f;
    #pragma unroll 4
    for (int f = 0; f < FOUT; ++f) {
        float w = wrow[f];
        s1 += w * a_src[h * FOUT + f];
        s2 += w * a_trg[h * FOUT + f];
    }
    Wc[h * D_IN + d]           = s1;
    Wc[(HEADS + h) * D_IN + d] = s2;
}

// ---------------------------------------------------------------------------
// Per-node scores: one wave per node, folded weights in registers.
__global__ void k_scores(const float* __restrict__ x,
                         const float* __restrict__ Wc,
                         float* __restrict__ ssrc,
                         float* __restrict__ strg, int N) {
    int lane   = threadIdx.x & 63;
    int wid    = blockIdx.x * (blockDim.x >> 6) + (threadIdx.x >> 6);
    int nwaves = gridDim.x * (blockDim.x >> 6);

    float w1[NOUT], w2[NOUT];
    #pragma unroll
    for (int o = 0; o < NOUT; ++o) {
        w1[o] = Wc[o * D_IN + lane];
        w2[o] = Wc[o * D_IN + 64 + lane];
    }

    for (int n = wid; n < N; n += nwaves) {
        float x1 = x[(size_t)n * D_IN + lane];
        float x2 = x[(size_t)n * D_IN + 64 + lane];
        float acc[NOUT];
        #pragma unroll
        for (int o = 0; o < NOUT; ++o)
            acc[o] = x1 * w1[o] + x2 * w2[o];
        #pragma unroll
        for (int o = 0; o < NOUT; ++o) {
            #pragma unroll
            for (int s = 32; s; s >>= 1)
                acc[o] += __shfl_xor(acc[o], s, 64);
        }
        if (lane < HEADS)           ssrc[(size_t)n * HEADS + lane]           = acc[lane];
        else if (lane < 2 * HEADS)  strg[(size_t)n * HEADS + (lane - HEADS)] = acc[lane];
    }
}

__device__ __forceinline__ void load_edge(const unsigned int* idx, int e, int E,
                                          bool is64, unsigned int& s, unsigned int& t) {
    if (is64) { s = idx[2 * (size_t)e]; t = idx[2 * ((size_t)E + e)]; }
    else      { s = idx[e];             t = idx[(size_t)E + e]; }
}

__device__ __forceinline__ void edge_scores(const float* ssrc, const float* strg,
                                            unsigned int s, unsigned int t, float* ex) {
    const float4* sp = (const float4*)(ssrc + (size_t)s * HEADS);
    const float4* tp = (const float4*)(strg + (size_t)t * HEADS);
    float4 sa = sp[0], sb = sp[1], ta = tp[0], tb = tp[1];
    float v[8] = { sa.x + ta.x, sa.y + ta.y, sa.z + ta.z, sa.w + ta.w,
                   sb.x + tb.x, sb.y + tb.y, sb.z + tb.z, sb.w + tb.w };
    #pragma unroll
    for (int h = 0; h < HEADS; ++h) {
        float sc = v[h];
        sc = sc > 0.f ? sc : 0.2f * sc;   // LeakyReLU(0.2)
        ex[h] = expf(sc);                 // |score| small; fp32 exp safe without max-sub
    }
}

// ---------------------------------------------------------------------------
// Edge pass 1 (XCD-local): atomics into this XCD's private copy of sums.
// Sub-device scope drops the device-coherent bypass, so the atomic executes
// in the XCD's L2 (shared by all CUs of this XCD -> correct for a private copy).
__global__ void k_edge_sum_xcd(const unsigned int* __restrict__ idx, int E, int NH,
                               const float* __restrict__ ssrc,
                               const float* __restrict__ strg,
                               float* __restrict__ sums8,
                               const unsigned int* __restrict__ flag) {
    unsigned int xcc;
    asm volatile("s_getreg_b32 %0, hwreg(HW_REG_XCC_ID)" : "=s"(xcc));
    float* base = sums8 + (size_t)(xcc & 7) * NH;

    int e = blockIdx.x * blockDim.x + threadIdx.x;
    if (e >= E) return;
    bool is64 = (*flag == 0u);
    unsigned int s, t;
    load_edge(idx, e, E, is64, s, t);
    float ex[8];
    edge_scores(ssrc, strg, s, t, ex);
    float* dst = base + (size_t)t * HEADS;
    #pragma unroll
    for (int h = 0; h < HEADS; ++h)
        __hip_atomic_fetch_add(dst + h, ex[h], __ATOMIC_RELAXED,
                               __HIP_MEMORY_SCOPE_WORKGROUP);
}

// Fallback (device-scope atomics into the single sums buffer).
__global__ void k_edge_sum(const unsigned int* __restrict__ idx, int E,
                           const float* __restrict__ ssrc,
                           const float* __restrict__ strg,
                           float* __restrict__ sums,
                           const unsigned int* __restrict__ flag) {
    int e = blockIdx.x * blockDim.x + threadIdx.x;
    if (e >= E) return;
    bool is64 = (*flag == 0u);
    unsigned int s, t;
    load_edge(idx, e, E, is64, s, t);
    float ex[8];
    edge_scores(ssrc, strg, s, t, ex);
    float* dst = sums + (size_t)t * HEADS;
    #pragma unroll
    for (int h = 0; h < HEADS; ++h)
        atomicAdd(dst + h, ex[h]);
}

// Fold the 8 XCD-private copies into the final sums buffer.
__global__ void k_reduce_sums(const float* __restrict__ sums8,
                              float* __restrict__ sums, int NH) {
    int i = (blockIdx.x * blockDim.x + threadIdx.x) * 4;
    if (i >= NH) return;
    float4 acc = *(const float4*)(sums8 + i);
    #pragma unroll
    for (int k = 1; k < 8; ++k) {
        float4 v = *(const float4*)(sums8 + (size_t)k * NH + i);
        acc.x += v.x; acc.y += v.y; acc.z += v.z; acc.w += v.w;
    }
    *(float4*)(sums + i) = acc;
}

// Edge pass 2: recompute exp and normalize.
__global__ void k_edge_out(const unsigned int* __restrict__ idx, int E,
                           const float* __restrict__ ssrc,
                           const float* __restrict__ strg,
                           const float* __restrict__ sums,
                           const unsigned int* __restrict__ flag,
                           float* __restrict__ out) {
    int e = blockIdx.x * blockDim.x + threadIdx.x;
    if (e >= E) return;
    bool is64 = (*flag == 0u);
    unsigned int s, t;
    load_edge(idx, e, E, is64, s, t);
    float ex[8];
    edge_scores(ssrc, strg, s, t, ex);
    const float4* sm = (const float4*)(sums + (size_t)t * HEADS);
    float4 m0 = sm[0], m1 = sm[1];
    float4 o0, o1;
    o0.x = ex[0] / (m0.x + 1e-16f);  o0.y = ex[1] / (m0.y + 1e-16f);
    o0.z = ex[2] / (m0.z + 1e-16f);  o0.w = ex[3] / (m0.w + 1e-16f);
    o1.x = ex[4] / (m1.x + 1e-16f);  o1.y = ex[5] / (m1.y + 1e-16f);
    o1.z = ex[6] / (m1.z + 1e-16f);  o1.w = ex[7] / (m1.w + 1e-16f);
    float4* op = (float4*)(out + (size_t)e * HEADS);
    op[0] = o0;
    op[1] = o1;
}

// ---------------------------------------------------------------------------
extern "C" void kernel_launch(void* const* d_in, const int* in_sizes, int n_in,
                              void* d_out, int out_size, void* d_ws, size_t ws_size,
                              hipStream_t stream) {
    const float*        x     = (const float*)d_in[0];
    const float*        W     = (const float*)d_in[1];
    const float*        a_src = (const float*)d_in[2];
    const float*        a_trg = (const float*)d_in[3];
    const unsigned int* idx   = (const unsigned int*)d_in[4];

    const int N  = in_sizes[0] / D_IN;   // 100000
    const int E  = in_sizes[4] / 2;      // 3200000
    const int NH = N * HEADS;

    float* out = (float*)d_out;

    // workspace layout: [sums NH][flag pad 256][ssrc NH][strg NH][Wc 8KB][sums8 8*NH]
    char*  ws   = (char*)d_ws;
    size_t NHb  = (size_t)NH * sizeof(float);
    float*        sums  = (float*)ws;
    unsigned int* flag  = (unsigned int*)(ws + NHb);
    float*        ssrc  = (float*)(ws + NHb + 256);
    float*        strg  = (float*)(ws + NHb + 256 + NHb);
    float*        Wc    = (float*)(ws + NHb + 256 + 2 * NHb);
    size_t        off8  = NHb + 256 + 2 * NHb + 16 * D_IN * sizeof(float);
    off8 = (off8 + 255) & ~(size_t)255;
    float*        sums8 = (float*)(ws + off8);
    const bool use_xcd = ws_size >= off8 + 8 * NHb;

    // zero atomic-sum region + flag (harness does not re-poison between replays)
    hipMemsetAsync(ws, 0, NHb + 256, stream);
    if (use_xcd)
        hipMemsetAsync(sums8, 0, 8 * NHb, stream);

    k_detect <<<1024, 256, 0, stream>>>(idx, in_sizes[4], flag);
    k_fold_w <<<(D_IN * HEADS + 255) / 256, 256, 0, stream>>>(W, a_src, a_trg, Wc);
    k_scores <<<2048, 256, 0, stream>>>(x, Wc, ssrc, strg, N);

    int eblocks = (E + 255) / 256;
    if (use_xcd) {
        k_edge_sum_xcd <<<eblocks, 256, 0, stream>>>(idx, E, NH, ssrc, strg, sums8, flag);
        k_reduce_sums  <<<(NH / 4 + 255) / 256, 256, 0, stream>>>(sums8, sums, NH);
    } else {
        k_edge_sum <<<eblocks, 256, 0, stream>>>(idx, E, ssrc, strg, sums, flag);
    }
    k_edge_out <<<eblocks, 256, 0, stream>>>(idx, E, ssrc, strg, sums, flag, out);
}

// Round 3
// 524.218 us; speedup vs baseline: 3.0456x; 3.0456x over previous
//
#include <hip/hip_runtime.h>

#define D_IN   128
#define HEADS  8
#define FOUT   64
#define NOUT   16     // 8 src + 8 trg folded outputs
#define NPB    128    // nodes per bin (local index fits in 7 bits)
#define NB_MAX 1024   // max bins (LDS histogram size)
#define CHUNK  8192   // edges per histogram/scatter block
#define NBLK_MAX 512  // max blocks in pass A/C (scan width)

// ---------------------------------------------------------------------------
// int32 vs int64 edge_index detection: if int64 (LE), odd 32-bit words of the
// src row are the zero high-halves.  flag==0 -> int64 ; flag!=0 -> int32.
__global__ void k_detect(const unsigned int* __restrict__ idx_w, int nwords,
                         unsigned int* __restrict__ flag) {
    unsigned int local = 0;
    int stride = gridDim.x * blockDim.x;
    for (int i = blockIdx.x * blockDim.x + threadIdx.x; 2 * i + 1 < nwords; i += stride)
        local |= idx_w[2 * i + 1];
    if (__any(local != 0) && (threadIdx.x & 63) == 0)
        atomicOr(flag, 1u);
}

__device__ __forceinline__ void load_edge(const unsigned int* idx, int e, int E,
                                          bool is64, unsigned int& s, unsigned int& t) {
    if (is64) { s = idx[2 * (size_t)e]; t = idx[2 * ((size_t)E + e)]; }
    else      { s = idx[e];             t = idx[(size_t)E + e]; }
}

__device__ __forceinline__ unsigned int load_trg(const unsigned int* idx, int e, int E,
                                                 bool is64) {
    return is64 ? idx[2 * ((size_t)E + e)] : idx[(size_t)E + e];
}

// ---------------------------------------------------------------------------
// Fold scoring vectors into the projection (Wc is [16][128] transposed).
__global__ void k_fold_w(const float* __restrict__ W,
                         const float* __restrict__ a_src,
                         const float* __restrict__ a_trg,
                         float* __restrict__ Wc) {
    int t = blockIdx.x * blockDim.x + threadIdx.x;
    if (t >= D_IN * HEADS) return;
    int d = t >> 3, h = t & 7;
    const float* wrow = W + d * (HEADS * FOUT) + h * FOUT;
    float s1 = 0.f, s2 = 0.f;
    #pragma unroll 4
    for (int f = 0; f < FOUT; ++f) {
        float w = wrow[f];
        s1 += w * a_src[h * FOUT + f];
        s2 += w * a_trg[h * FOUT + f];
    }
    Wc[h * D_IN + d]           = s1;
    Wc[(HEADS + h) * D_IN + d] = s2;
}

// ---------------------------------------------------------------------------
// Per-node scores: one wave per node, folded weights in registers.
__global__ void k_scores(const float* __restrict__ x,
                         const float* __restrict__ Wc,
                         float* __restrict__ ssrc,
                         float* __restrict__ strg, int N) {
    int lane   = threadIdx.x & 63;
    int wid    = blockIdx.x * (blockDim.x >> 6) + (threadIdx.x >> 6);
    int nwaves = gridDim.x * (blockDim.x >> 6);

    float w1[NOUT], w2[NOUT];
    #pragma unroll
    for (int o = 0; o < NOUT; ++o) {
        w1[o] = Wc[o * D_IN + lane];
        w2[o] = Wc[o * D_IN + 64 + lane];
    }

    for (int n = wid; n < N; n += nwaves) {
        float x1 = x[(size_t)n * D_IN + lane];
        float x2 = x[(size_t)n * D_IN + 64 + lane];
        float acc[NOUT];
        #pragma unroll
        for (int o = 0; o < NOUT; ++o)
            acc[o] = x1 * w1[o] + x2 * w2[o];
        #pragma unroll
        for (int o = 0; o < NOUT; ++o) {
            #pragma unroll
            for (int s = 32; s; s >>= 1)
                acc[o] += __shfl_xor(acc[o], s, 64);
        }
        if (lane < HEADS)           ssrc[(size_t)n * HEADS + lane]           = acc[lane];
        else if (lane < 2 * HEADS)  strg[(size_t)n * HEADS + (lane - HEADS)] = acc[lane];
    }
}

__device__ __forceinline__ void edge_scores(const float* ssrc, const float* strg,
                                            unsigned int s, unsigned int t, float* ex) {
    const float4* sp = (const float4*)(ssrc + (size_t)s * HEADS);
    const float4* tp = (const float4*)(strg + (size_t)t * HEADS);
    float4 sa = sp[0], sb = sp[1], ta = tp[0], tb = tp[1];
    float v[8] = { sa.x + ta.x, sa.y + ta.y, sa.z + ta.z, sa.w + ta.w,
                   sb.x + tb.x, sb.y + tb.y, sb.z + tb.z, sb.w + tb.w };
    #pragma unroll
    for (int h = 0; h < HEADS; ++h) {
        float sc = v[h];
        sc = sc > 0.f ? sc : 0.2f * sc;   // LeakyReLU(0.2)
        ex[h] = expf(sc);                 // |score| small; fp32 exp safe without max-sub
    }
}

// ---------------------------------------------------------------------------
// Pass A: per-block LDS histogram of coarse target bins (bin = trg >> 7).
__global__ void k_hist(const unsigned int* __restrict__ idx, int E,
                       const unsigned int* __restrict__ flag,
                       int* __restrict__ histM, int NB) {
    __shared__ int h[NB_MAX];
    for (int i = threadIdx.x; i < NB; i += blockDim.x) h[i] = 0;
    __syncthreads();
    bool is64 = (*flag == 0u);
    int base = blockIdx.x * CHUNK;
    int lim  = min(base + CHUNK, E);
    for (int e = base + threadIdx.x; e < lim; e += blockDim.x) {
        unsigned int t = load_trg(idx, e, E, is64);
        atomicAdd(&h[t >> 7], 1);
    }
    __syncthreads();
    for (int i = threadIdx.x; i < NB; i += blockDim.x)
        histM[(size_t)blockIdx.x * NB + i] = h[i];
}

// Pass B1: per-bin exclusive scan over blocks; emits per-bin totals.
// grid = NB blocks, blockDim = 512 (NBLK <= 512).
__global__ void k_scan_blocks(int* __restrict__ histM, int NB, int NBLK,
                              int* __restrict__ binTotal) {
    int b = blockIdx.x;
    __shared__ int v[NBLK_MAX];
    int tid = threadIdx.x;
    v[tid] = (tid < NBLK) ? histM[(size_t)tid * NB + b] : 0;
    __syncthreads();
    for (int off = 1; off < NBLK_MAX; off <<= 1) {
        int t = (tid >= off) ? v[tid - off] : 0;
        __syncthreads();
        v[tid] += t;
        __syncthreads();
    }
    if (tid < NBLK)
        histM[(size_t)tid * NB + b] = tid ? v[tid - 1] : 0;   // exclusive within bin
    if (tid == 0)
        binTotal[b] = v[NBLK - 1];
}

// Pass B2: exclusive scan over bins. single block, blockDim = NB_MAX.
__global__ void k_scan_bins(const int* __restrict__ binTotal, int NB,
                            int* __restrict__ binBase) {
    __shared__ int v[NB_MAX];
    int tid = threadIdx.x;
    v[tid] = (tid < NB) ? binTotal[tid] : 0;
    __syncthreads();
    for (int off = 1; off < NB_MAX; off <<= 1) {
        int t = (tid >= off) ? v[tid - off] : 0;
        __syncthreads();
        v[tid] += t;
        __syncthreads();
    }
    if (tid < NB)
        binBase[tid] = tid ? v[tid - 1] : 0;
}

// Pass C: scatter packed edge records into bin order.
// record = src | (trg & 127) << 20   (needs N < 2^20)
__global__ void k_scatter(const unsigned int* __restrict__ idx, int E,
                          const unsigned int* __restrict__ flag,
                          const int* __restrict__ histM, int NB,
                          const int* __restrict__ binBase,
                          unsigned int* __restrict__ binned) {
    __shared__ int cnt[NB_MAX];
    for (int i = threadIdx.x; i < NB; i += blockDim.x)
        cnt[i] = binBase[i] + histM[(size_t)blockIdx.x * NB + i];
    __syncthreads();
    bool is64 = (*flag == 0u);
    int base = blockIdx.x * CHUNK;
    int lim  = min(base + CHUNK, E);
    for (int e = base + threadIdx.x; e < lim; e += blockDim.x) {
        unsigned int s, t;
        load_edge(idx, e, E, is64, s, t);
        int pos = atomicAdd(&cnt[t >> 7], 1);
        binned[pos] = s | ((t & 127u) << 20);
    }
}

// Pass D: per-bin segment sums via LDS accumulation (no global atomics).
// grid = NB blocks; strg for the bin's nodes preloaded; head-major LDS layout.
__global__ void k_binsum(const unsigned int* __restrict__ binned,
                         const int* __restrict__ binBase,
                         const int* __restrict__ binTotal,
                         const float* __restrict__ ssrc,
                         const float* __restrict__ strg,
                         float* __restrict__ sums, int N, int NB) {
    __shared__ float ssum[HEADS * NPB];
    __shared__ float stl [HEADS * NPB];
    int b = blockIdx.x;
    int node0 = b << 7;
    int nn = min(NPB, N - node0);

    for (int i = threadIdx.x; i < HEADS * NPB; i += blockDim.x) ssum[i] = 0.f;
    for (int i = threadIdx.x; i < nn * HEADS; i += blockDim.x) {
        int n = i >> 3, h = i & 7;
        stl[h * NPB + n] = strg[(size_t)(node0 + n) * HEADS + h];
    }
    __syncthreads();

    int start = binBase[b];
    int end   = start + binTotal[b];
    for (int e = start + (int)threadIdx.x; e < end; e += blockDim.x) {
        unsigned int v = binned[e];
        unsigned int s = v & 0xFFFFFu;
        unsigned int l = v >> 20;
        const float4* sp = (const float4*)(ssrc + (size_t)s * HEADS);
        float4 sa = sp[0], sb = sp[1];
        float vs[8] = { sa.x, sa.y, sa.z, sa.w, sb.x, sb.y, sb.z, sb.w };
        #pragma unroll
        for (int h = 0; h < HEADS; ++h) {
            float sc = vs[h] + stl[h * NPB + l];
            sc = sc > 0.f ? sc : 0.2f * sc;
            atomicAdd(&ssum[h * NPB + l], expf(sc));
        }
    }
    __syncthreads();

    for (int i = threadIdx.x; i < nn * HEADS; i += blockDim.x) {
        int n = i >> 3, h = i & 7;
        sums[(size_t)(node0 + n) * HEADS + h] = ssum[h * NPB + n];
    }
}

// ---------------------------------------------------------------------------
// Fallback edge pass 1 (device atomics) when workspace/shape doesn't fit.
__global__ void k_edge_sum(const unsigned int* __restrict__ idx, int E,
                           const float* __restrict__ ssrc,
                           const float* __restrict__ strg,
                           float* __restrict__ sums,
                           const unsigned int* __restrict__ flag) {
    int e = blockIdx.x * blockDim.x + threadIdx.x;
    if (e >= E) return;
    bool is64 = (*flag == 0u);
    unsigned int s, t;
    load_edge(idx, e, E, is64, s, t);
    float ex[8];
    edge_scores(ssrc, strg, s, t, ex);
    float* dst = sums + (size_t)t * HEADS;
    #pragma unroll
    for (int h = 0; h < HEADS; ++h)
        atomicAdd(dst + h, ex[h]);
}

// Edge pass 2: recompute exp and normalize.
__global__ void k_edge_out(const unsigned int* __restrict__ idx, int E,
                           const float* __restrict__ ssrc,
                           const float* __restrict__ strg,
                           const float* __restrict__ sums,
                           const unsigned int* __restrict__ flag,
                           float* __restrict__ out) {
    int e = blockIdx.x * blockDim.x + threadIdx.x;
    if (e >= E) return;
    bool is64 = (*flag == 0u);
    unsigned int s, t;
    load_edge(idx, e, E, is64, s, t);
    float ex[8];
    edge_scores(ssrc, strg, s, t, ex);
    const float4* sm = (const float4*)(sums + (size_t)t * HEADS);
    float4 m0 = sm[0], m1 = sm[1];
    float4 o0, o1;
    o0.x = ex[0] / (m0.x + 1e-16f);  o0.y = ex[1] / (m0.y + 1e-16f);
    o0.z = ex[2] / (m0.z + 1e-16f);  o0.w = ex[3] / (m0.w + 1e-16f);
    o1.x = ex[4] / (m1.x + 1e-16f);  o1.y = ex[5] / (m1.y + 1e-16f);
    o1.z = ex[6] / (m1.z + 1e-16f);  o1.w = ex[7] / (m1.w + 1e-16f);
    float4* op = (float4*)(out + (size_t)e * HEADS);
    op[0] = o0;
    op[1] = o1;
}

// ---------------------------------------------------------------------------
extern "C" void kernel_launch(void* const* d_in, const int* in_sizes, int n_in,
                              void* d_out, int out_size, void* d_ws, size_t ws_size,
                              hipStream_t stream) {
    const float*        x     = (const float*)d_in[0];
    const float*        W     = (const float*)d_in[1];
    const float*        a_src = (const float*)d_in[2];
    const float*        a_trg = (const float*)d_in[3];
    const unsigned int* idx   = (const unsigned int*)d_in[4];

    const int N  = in_sizes[0] / D_IN;   // 100000
    const int E  = in_sizes[4] / 2;      // 3200000
    const int NH = N * HEADS;
    const int NB   = (N + NPB - 1) / NPB;     // 782
    const int NBLK = (E + CHUNK - 1) / CHUNK; // 391

    float* out = (float*)d_out;

    // workspace layout (256B-aligned segments)
    char*  ws  = (char*)d_ws;
    size_t off = 0;
    auto alloc = [&](size_t bytes) { size_t o = off; off = (off + bytes + 255) & ~(size_t)255; return o; };
    size_t NHb = (size_t)NH * sizeof(float);
    float*        sums     = (float*)(ws + alloc(NHb));
    unsigned int* flag     = (unsigned int*)(ws + alloc(4));
    float*        ssrc     = (float*)(ws + alloc(NHb));
    float*        strg     = (float*)(ws + alloc(NHb));
    float*        Wc       = (float*)(ws + alloc(NOUT * D_IN * sizeof(float)));
    int*          histM    = (int*)(ws + alloc((size_t)NBLK * NB * sizeof(int)));
    int*          binTotal = (int*)(ws + alloc((size_t)NB * sizeof(int)));
    int*          binBase  = (int*)(ws + alloc((size_t)NB * sizeof(int)));
    unsigned int* binned   = (unsigned int*)(ws + alloc((size_t)E * sizeof(unsigned int)));

    const bool fast = (off <= ws_size) && (NB <= NB_MAX) && (NBLK <= NBLK_MAX)
                      && (N < (1 << 20));

    // zero flag (and sums for the fallback's atomics)
    hipMemsetAsync(flag, 0, 256, stream);
    if (!fast)
        hipMemsetAsync(sums, 0, NHb, stream);

    k_detect <<<1024, 256, 0, stream>>>(idx, in_sizes[4], flag);
    k_fold_w <<<(D_IN * HEADS + 255) / 256, 256, 0, stream>>>(W, a_src, a_trg, Wc);
    k_scores <<<2048, 256, 0, stream>>>(x, Wc, ssrc, strg, N);

    int eblocks = (E + 255) / 256;
    if (fast) {
        k_hist        <<<NBLK, 256, 0, stream>>>(idx, E, flag, histM, NB);
        k_scan_blocks <<<NB, NBLK_MAX, 0, stream>>>(histM, NB, NBLK, binTotal);
        k_scan_bins   <<<1, NB_MAX, 0, stream>>>(binTotal, NB, binBase);
        k_scatter     <<<NBLK, 256, 0, stream>>>(idx, E, flag, histM, NB, binBase, binned);
        k_binsum      <<<NB, 256, 0, stream>>>(binned, binBase, binTotal, ssrc, strg,
                                               sums, N, NB);
    } else {
        k_edge_sum <<<eblocks, 256, 0, stream>>>(idx, E, ssrc, strg, sums, flag);
    }
    k_edge_out <<<eblocks, 256, 0, stream>>>(idx, E, ssrc, strg, sums, flag, out);
}